// Round 1
// baseline (497.559 us; speedup 1.0000x reference)
//
#include <hip/hip_runtime.h>

typedef unsigned short u16;
typedef __bf16 bf16x8 __attribute__((ext_vector_type(8)));
typedef float f32x4 __attribute__((ext_vector_type(4)));
typedef unsigned short ushort8 __attribute__((ext_vector_type(8)));

__device__ __forceinline__ void gload_lds16(const void* g, void* l) {
  __builtin_amdgcn_global_load_lds(
      (const __attribute__((address_space(1))) void*)g,
      (__attribute__((address_space(3))) void*)l, 16, 0, 0);
}

__device__ __forceinline__ u16 f2bf(float f) {
  unsigned int u = __builtin_bit_cast(unsigned int, f);
  u = (u + 0x7fffu + ((u >> 16) & 1u)) >> 16;
  return (u16)u;
}

// ---------------- cast f32 -> bf16 ----------------
__global__ void castk(const float* __restrict__ in, u16* __restrict__ out, int n) {
  size_t i = ((size_t)blockIdx.x * 256 + threadIdx.x) * 8;
  if (i >= (size_t)n) return;
  const float4* p = (const float4*)(in + i);
  float4 a = p[0], b = p[1];
  ushort8 o;
  o[0] = f2bf(a.x); o[1] = f2bf(a.y); o[2] = f2bf(a.z); o[3] = f2bf(a.w);
  o[4] = f2bf(b.x); o[5] = f2bf(b.y); o[6] = f2bf(b.z); o[7] = f2bf(b.w);
  *(ushort8*)(out + i) = o;
}

// ---------------- GEMM: C[m,n] = act(A[m,:] . W[n,:] + bias[n]) ----------------
// A: [M,K] bf16 row-major; W: [N,K] bf16 row-major (NT). 128x128 tile, BK=64.
// LDS layout: element (row,col) at byte row*128 + ((col*2) ^ ((row&7)<<4)).
// Staged via global_load_lds (linear dest) with pre-swizzled global source.
template<int OUT_BF16, int RELU>
__global__ __launch_bounds__(256, 2)
void gemm_nt(const u16* __restrict__ A, const u16* __restrict__ W,
             const float* __restrict__ bias, void* __restrict__ C,
             int M, int N, int K)
{
  __shared__ u16 As[128 * 64];
  __shared__ u16 Bs[128 * 64];
  const int tid = threadIdx.x;
  const int w = tid >> 6, l = tid & 63;
  const int nbn = N >> 7;
  const int bm = blockIdx.x / nbn, bn = blockIdx.x % nbn;
  const int wm = w >> 1, wn = w & 1;

  f32x4 acc[4][4] = {};

  const int lr = l >> 3;                      // 0..7
  const int lc = ((l & 7) ^ lr) << 3;         // swizzled col block (elems)
  const u16* aG = A + (size_t)(bm * 128) * K + lc;
  const u16* wG = W + (size_t)(bn * 128) * K + lc;

  const int nk = K >> 6;
  for (int kt = 0; kt < nk; ++kt) {
    __syncthreads();
#pragma unroll
    for (int i = 0; i < 4; ++i) {
      int c = w * 4 + i;                      // chunk 0..15 (1KB each)
      int row = c * 8 + lr;
      gload_lds16(aG + (size_t)row * K + kt * 64, &As[c * 512]);
      gload_lds16(wG + (size_t)row * K + kt * 64, &Bs[c * 512]);
    }
    __syncthreads();
#pragma unroll
    for (int kk = 0; kk < 2; ++kk) {
      bf16x8 af[4], bfv[4];
#pragma unroll
      for (int mi = 0; mi < 4; ++mi) {
        int row = wm * 64 + mi * 16 + (l & 15);
        int off = row * 128 + ((kk * 64 + ((l >> 4) << 4)) ^ ((row & 7) << 4));
        af[mi] = *(const bf16x8*)((const char*)As + off);
      }
#pragma unroll
      for (int ni = 0; ni < 4; ++ni) {
        int row = wn * 64 + ni * 16 + (l & 15);
        int off = row * 128 + ((kk * 64 + ((l >> 4) << 4)) ^ ((row & 7) << 4));
        bfv[ni] = *(const bf16x8*)((const char*)Bs + off);
      }
#pragma unroll
      for (int mi = 0; mi < 4; ++mi)
#pragma unroll
        for (int ni = 0; ni < 4; ++ni)
          acc[mi][ni] = __builtin_amdgcn_mfma_f32_16x16x32_bf16(af[mi], bfv[ni], acc[mi][ni], 0, 0, 0);
    }
  }

  const int rowb = bm * 128 + wm * 64 + ((l >> 4) << 2);
  const int colb = bn * 128 + wn * 64 + (l & 15);
#pragma unroll
  for (int ni = 0; ni < 4; ++ni) {
    float bv = bias[colb + ni * 16];
#pragma unroll
    for (int mi = 0; mi < 4; ++mi) {
#pragma unroll
      for (int r = 0; r < 4; ++r) {
        float v = acc[mi][ni][r] + bv;
        if (RELU) v = fmaxf(v, 0.f);
        size_t idx = (size_t)(rowb + mi * 16 + r) * N + colb + ni * 16;
        if (OUT_BF16) ((u16*)C)[idx] = f2bf(v);
        else          ((float*)C)[idx] = v;
      }
    }
  }
}

// ---------------- fused attention: F += softmax(QK^T/8) V  (per b,h) ----------------
// grid = B*H*(S/64); block 256 (4 waves, 16 q-rows each)
__global__ __launch_bounds__(256, 2)
void attn_kernel(const u16* __restrict__ Q, const u16* __restrict__ Kx,
                 const u16* __restrict__ V, float* __restrict__ F)
{
  const int S = 512, D = 512;
  __shared__ u16 Qs[64 * 64];
  __shared__ u16 Ks[64 * 64];
  __shared__ u16 Vs[64 * 64];   // [d][k], swizzled
  __shared__ u16 Ps[64 * 64];   // [q][k], swizzled

  const int tid = threadIdx.x, w = tid >> 6, l = tid & 63;
  int idx = blockIdx.x;
  const int qt = idx & 7; idx >>= 3;
  const int h  = idx & 7; idx >>= 3;
  const int b  = idx;

  const int lr = l >> 3, lc = ((l & 7) ^ lr) << 3;
  const size_t hoff = (size_t)h * 64;

  const u16* qG = Q + ((size_t)(b * S + qt * 64)) * D + hoff + lc;
#pragma unroll
  for (int i = 0; i < 2; ++i) {
    int c = w * 2 + i;
    gload_lds16(qG + (size_t)(c * 8 + lr) * D, &Qs[c * 512]);
  }

  f32x4 o_acc[4] = {};
  float m_run[4], lsum[4];
#pragma unroll
  for (int r = 0; r < 4; ++r) { m_run[r] = -1e30f; lsum[r] = 0.f; }

  const u16* kG = Kx + (size_t)(b * S) * D + hoff + lc;
  const int vk = tid >> 2;              // 0..63
  const int vd0 = (tid & 3) << 4;       // 0,16,32,48
  const u16* vG = V + (size_t)(b * S) * D + hoff;

  for (int kt = 0; kt < 8; ++kt) {
    __syncthreads();
#pragma unroll
    for (int i = 0; i < 2; ++i) {
      int c = w * 2 + i;
      gload_lds16(kG + (size_t)(kt * 64 + c * 8 + lr) * D, &Ks[c * 512]);
    }
    {
      const u16* vp = vG + (size_t)(kt * 64 + vk) * D + vd0;
      ushort8 v0 = *(const ushort8*)vp;
      ushort8 v1 = *(const ushort8*)(vp + 8);
#pragma unroll
      for (int j = 0; j < 8; ++j) {
        int d = vd0 + j;
        int sw = ((d ^ (d >> 3)) & 7) << 4;
        *(u16*)((char*)Vs + d * 128 + ((vk * 2) ^ sw)) = v0[j];
        d = vd0 + 8 + j;
        sw = ((d ^ (d >> 3)) & 7) << 4;
        *(u16*)((char*)Vs + d * 128 + ((vk * 2) ^ sw)) = v1[j];
      }
    }
    __syncthreads();

    // QK^T -> sacc[ni] covers 16 k-cols each
    f32x4 sacc[4] = {};
#pragma unroll
    for (int kk = 0; kk < 2; ++kk) {
      int qrow = w * 16 + (l & 15);
      int qoff = qrow * 128 + ((kk * 64 + ((l >> 4) << 4)) ^ ((qrow & 7) << 4));
      bf16x8 qa = *(const bf16x8*)((const char*)Qs + qoff);
#pragma unroll
      for (int ni = 0; ni < 4; ++ni) {
        int krow = ni * 16 + (l & 15);
        int koff = krow * 128 + ((kk * 64 + ((l >> 4) << 4)) ^ ((krow & 7) << 4));
        bf16x8 kb = *(const bf16x8*)((const char*)Ks + koff);
        sacc[ni] = __builtin_amdgcn_mfma_f32_16x16x32_bf16(qa, kb, sacc[ni], 0, 0, 0);
      }
    }

    // online softmax per owned row; write P (bf16, swizzled)
#pragma unroll
    for (int r = 0; r < 4; ++r) {
      float s0 = sacc[0][r] * 0.125f, s1 = sacc[1][r] * 0.125f;
      float s2 = sacc[2][r] * 0.125f, s3 = sacc[3][r] * 0.125f;
      float tm = fmaxf(fmaxf(s0, s1), fmaxf(s2, s3));
#pragma unroll
      for (int m = 1; m < 16; m <<= 1) tm = fmaxf(tm, __shfl_xor(tm, m));
      float mn = fmaxf(m_run[r], tm);
      float sc = __expf(m_run[r] - mn);
      m_run[r] = mn;
      float p0 = __expf(s0 - mn), p1 = __expf(s1 - mn);
      float p2 = __expf(s2 - mn), p3 = __expf(s3 - mn);
      lsum[r] = lsum[r] * sc + (p0 + p1 + p2 + p3);
#pragma unroll
      for (int ni = 0; ni < 4; ++ni) o_acc[ni][r] *= sc;
      int q = w * 16 + ((l >> 4) << 2) + r;
      int sw = ((q ^ (q >> 3)) & 7) << 4;
      int col = (l & 15) * 2;
      char* pb = (char*)Ps + q * 128;
      *(u16*)(pb + ((0 + col) ^ sw))   = f2bf(p0);
      *(u16*)(pb + ((32 + col) ^ sw))  = f2bf(p1);
      *(u16*)(pb + ((64 + col) ^ sw))  = f2bf(p2);
      *(u16*)(pb + ((96 + col) ^ sw))  = f2bf(p3);
    }
    __syncthreads();

    // PV
#pragma unroll
    for (int kk = 0; kk < 2; ++kk) {
      int q = w * 16 + (l & 15);
      int sp = ((q ^ (q >> 3)) & 7) << 4;
      int poff = q * 128 + ((kk * 64 + ((l >> 4) << 4)) ^ sp);
      bf16x8 pa = *(const bf16x8*)((const char*)Ps + poff);
#pragma unroll
      for (int ni = 0; ni < 4; ++ni) {
        int d = ni * 16 + (l & 15);
        int sv = ((d ^ (d >> 3)) & 7) << 4;
        int voff = d * 128 + ((kk * 64 + ((l >> 4) << 4)) ^ sv);
        bf16x8 vb = *(const bf16x8*)((const char*)Vs + voff);
        o_acc[ni] = __builtin_amdgcn_mfma_f32_16x16x32_bf16(pa, vb, o_acc[ni], 0, 0, 0);
      }
    }
  }

#pragma unroll
  for (int r = 0; r < 4; ++r) {
    float t = lsum[r];
#pragma unroll
    for (int m = 1; m < 16; m <<= 1) t += __shfl_xor(t, m);
    lsum[r] = 1.f / t;
  }
#pragma unroll
  for (int ni = 0; ni < 4; ++ni) {
    int col = ni * 16 + (l & 15);
#pragma unroll
    for (int r = 0; r < 4; ++r) {
      int qrow = qt * 64 + w * 16 + ((l >> 4) << 2) + r;
      float* fp = F + ((size_t)(b * S + qrow)) * D + h * 64 + col;
      *fp += o_acc[ni][r] * lsum[r];
    }
  }
}

// ---------------- LayerNorm (row=512), optional residual add, dual output ----------------
__global__ __launch_bounds__(256)
void ln_kernel(const float* __restrict__ in, const float* __restrict__ resid,
               const float* __restrict__ gamma, const float* __restrict__ beta,
               float* __restrict__ outf, u16* __restrict__ outb)
{
  const int l = threadIdx.x & 63;
  const size_t row = (size_t)blockIdx.x * 4 + (threadIdx.x >> 6);
  const float4* p4 = (const float4*)(in + row * 512);
  float4 a = p4[l * 2], c = p4[l * 2 + 1];
  float x[8] = {a.x, a.y, a.z, a.w, c.x, c.y, c.z, c.w};
  if (resid) {
    const float4* r4 = (const float4*)(resid + row * 512);
    float4 ra = r4[l * 2], rc = r4[l * 2 + 1];
    x[0] += ra.x; x[1] += ra.y; x[2] += ra.z; x[3] += ra.w;
    x[4] += rc.x; x[5] += rc.y; x[6] += rc.z; x[7] += rc.w;
  }
  float s = 0.f, ss = 0.f;
#pragma unroll
  for (int j = 0; j < 8; ++j) { s += x[j]; ss += x[j] * x[j]; }
#pragma unroll
  for (int m = 1; m < 64; m <<= 1) { s += __shfl_xor(s, m); ss += __shfl_xor(ss, m); }
  float mean = s * (1.f / 512.f);
  float var = fmaxf((ss - 512.f * mean * mean) * (1.f / 511.f), 0.f);
  float inv = 1.f / (sqrtf(var) + 1e-8f);
  const float4* g4 = (const float4*)gamma;
  const float4* b4 = (const float4*)beta;
  float4 g0 = g4[l * 2], g1 = g4[l * 2 + 1];
  float4 b0 = b4[l * 2], b1 = b4[l * 2 + 1];
  float gg[8] = {g0.x, g0.y, g0.z, g0.w, g1.x, g1.y, g1.z, g1.w};
  float bb[8] = {b0.x, b0.y, b0.z, b0.w, b1.x, b1.y, b1.z, b1.w};
  float y[8];
#pragma unroll
  for (int j = 0; j < 8; ++j) y[j] = gg[j] * (x[j] - mean) * inv + bb[j];
  if (outf) {
    float4* o4 = (float4*)(outf + row * 512);
    o4[l * 2]     = make_float4(y[0], y[1], y[2], y[3]);
    o4[l * 2 + 1] = make_float4(y[4], y[5], y[6], y[7]);
  }
  if (outb) {
    ushort8 o;
#pragma unroll
    for (int j = 0; j < 8; ++j) o[j] = f2bf(y[j]);
    *(ushort8*)(outb + row * 512 + l * 8) = o;
  }
}

extern "C" void kernel_launch(void* const* d_in, const int* in_sizes, int n_in,
                              void* d_out, int out_size, void* d_ws, size_t ws_size,
                              hipStream_t stream)
{
  const int B = 32, S = 512, D = 512, NB = 2, DF = 2048;
  const int M = B * S;

  const float* x   = (const float*)d_in[0];
  const float* wq  = (const float*)d_in[1];
  const float* bq  = (const float*)d_in[2];
  const float* wk  = (const float*)d_in[3];
  const float* bk  = (const float*)d_in[4];
  const float* wv  = (const float*)d_in[5];
  const float* bv  = (const float*)d_in[6];
  const float* wr  = (const float*)d_in[7];
  const float* br  = (const float*)d_in[8];
  const float* ga  = (const float*)d_in[9];
  const float* ba  = (const float*)d_in[10];
  const float* wc1 = (const float*)d_in[11];
  const float* bc1 = (const float*)d_in[12];
  const float* wc2 = (const float*)d_in[13];
  const float* bc2 = (const float*)d_in[14];
  const float* gf  = (const float*)d_in[15];
  const float* bfp = (const float*)d_in[16];

  char* ws = (char*)d_ws;
  u16*   curb = (u16*)(ws + 0);                         // 16 MB  (bf16 activations)
  float* F    = (float*)(ws + 16777216);                // 32 MB  (preLN / also Y)
  float* G    = (float*)(ws + 50331648);                // 32 MB  (LN1 f32 out)
  u16*   Hh   = (u16*)(ws + 83886080);                  // 16 MB  (LN1 bf16 out)
  u16*   wqb  = (u16*)(ws + 100663296);
  u16*   wkb  = wqb + (size_t)NB * D * D;
  u16*   wvb  = wkb + (size_t)NB * D * D;
  u16*   wrb  = wvb + (size_t)NB * D * D;
  u16*   wc1b = wrb + (size_t)NB * D * D;
  u16*   wc2b = wc1b + (size_t)NB * DF * D;
  u16*   Qb   = (u16*)(ws + 113246208);
  u16*   Kb   = Qb + (size_t)M * D;
  u16*   Vb   = Kb + (size_t)M * D;
  u16*   Ih   = Qb;        // aliases Q/K/V (dead by FFN1)
  float* Y    = F;         // aliases F (dead by FFN2)

  // casts
  castk<<<M * D / 2048, 256, 0, stream>>>(x, curb, M * D);
  castk<<<NB * D * D / 2048, 256, 0, stream>>>(wq, wqb, NB * D * D);
  castk<<<NB * D * D / 2048, 256, 0, stream>>>(wk, wkb, NB * D * D);
  castk<<<NB * D * D / 2048, 256, 0, stream>>>(wv, wvb, NB * D * D);
  castk<<<NB * D * D / 2048, 256, 0, stream>>>(wr, wrb, NB * D * D);
  castk<<<NB * DF * D / 2048, 256, 0, stream>>>(wc1, wc1b, NB * DF * D);
  castk<<<NB * DF * D / 2048, 256, 0, stream>>>(wc2, wc2b, NB * DF * D);

  const int gD  = (M / 128) * (D / 128);    // 512
  const int gDF = (M / 128) * (DF / 128);   // 2048

  for (int i = 0; i < NB; ++i) {
    const size_t wo  = (size_t)i * D * D;
    const size_t wfo = (size_t)i * DF * D;
    gemm_nt<1, 1><<<gD, 256, 0, stream>>>(curb, wqb + wo, bq + i * D, Qb, M, D, D);
    gemm_nt<1, 1><<<gD, 256, 0, stream>>>(curb, wkb + wo, bk + i * D, Kb, M, D, D);
    gemm_nt<1, 1><<<gD, 256, 0, stream>>>(curb, wvb + wo, bv + i * D, Vb, M, D, D);
    gemm_nt<0, 1><<<gD, 256, 0, stream>>>(curb, wrb + wo, br + i * D, F,  M, D, D);
    attn_kernel<<<B * 8 * 8, 256, 0, stream>>>(Qb, Kb, Vb, F);
    ln_kernel<<<M / 4, 256, 0, stream>>>(F, nullptr, ga + i * D, ba + i * D, G, Hh);
    gemm_nt<1, 1><<<gDF, 256, 0, stream>>>(Hh, wc1b + wfo, bc1 + i * DF, Ih, M, DF, D);
    gemm_nt<0, 0><<<gD, 256, 0, stream>>>(Ih, wc2b + wfo, bc2 + i * D, Y, M, D, DF);
    ln_kernel<<<M / 4, 256, 0, stream>>>(Y, G, gf + i * D, bfp + i * D,
                                         (i == NB - 1) ? (float*)d_out : nullptr, curb);
  }
}